// Round 3
// baseline (456.671 us; speedup 1.0000x reference)
//
#include <hip/hip_runtime.h>
#include <math.h>

#define B_   8
#define C_   128
#define E_   8
#define HW_  4096

typedef unsigned short u16;
typedef unsigned int   u32;
typedef __attribute__((ext_vector_type(8))) short bf16x8;
typedef __attribute__((ext_vector_type(4))) float f32x4;

__device__ __forceinline__ u16 f2bf(float f) {
  u32 u = __float_as_uint(f);
  u32 r = (u + 0x7fffu + ((u >> 16) & 1u)) >> 16;
  return (u16)r;
}
__device__ __forceinline__ float bf2f(u16 h) {
  return __uint_as_float(((u32)h) << 16);
}
#define MFMA(a, b, c) __builtin_amdgcn_mfma_f32_16x16x32_bf16(a, b, c, 0, 0, 0)

// ---------------- channel means ----------------
__global__ __launch_bounds__(256) void k_mean(const float* __restrict__ x,
                                              float* __restrict__ x0) {
  int bc = blockIdx.x;
  const float4* p = (const float4*)(x + (size_t)bc * HW_);
  float s = 0.f;
  for (int i = threadIdx.x; i < HW_ / 4; i += 256) {
    float4 v = p[i];
    s += v.x + v.y + v.z + v.w;
  }
#pragma unroll
  for (int off = 32; off > 0; off >>= 1) s += __shfl_down(s, off);
  __shared__ float red[4];
  if ((threadIdx.x & 63) == 0) red[threadIdx.x >> 6] = s;
  __syncthreads();
  if (threadIdx.x == 0)
    x0[bc] = (red[0] + red[1] + red[2] + red[3]) * (1.f / HW_);
}

// ---------------- gates (UNCHANGED math — absmax source, keep identical) --------
__global__ __launch_bounds__(256) void k_gate(const float* __restrict__ x0,
    const float* __restrict__ g1, const float* __restrict__ g2,
    const float* __restrict__ g3, const float* __restrict__ g4,
    float* __restrict__ wmat, float* __restrict__ w2, int* __restrict__ idxb,
    int* __restrict__ needed, float* __restrict__ lossp) {
  __shared__ float go[4][8][8];
  int t = threadIdx.x;
  int g = t >> 6, b = (t >> 3) & 7, e = t & 7;
  const float* gp = (g == 0) ? g1 : (g == 1) ? g2 : (g == 2) ? g3 : g4;
  const float* xr = x0 + b * C_;
  float s = 0.f;
  for (int c = 0; c < C_; ++c) s += xr[c] * gp[c * E_ + e];
  go[g][b][e] = s;
  wmat[t] = 0.f;
  if (t < 64) needed[t] = 0;
  __syncthreads();
  if (t < 32) {
    int gg = t >> 3, bb = t & 7;
    float m = -1e30f;
#pragma unroll
    for (int k = 0; k < 8; ++k) m = fmaxf(m, go[gg][bb][k]);
    float tmp[8]; float sum = 0.f;
#pragma unroll
    for (int k = 0; k < 8; ++k) { tmp[k] = expf(go[gg][bb][k] - m); sum += tmp[k]; }
    float inv = 1.f / sum;
#pragma unroll
    for (int k = 0; k < 8; ++k) { tmp[k] *= inv; go[gg][bb][k] = tmp[k]; }
    float v0 = -1.f; int i0 = 0;
#pragma unroll
    for (int k = 0; k < 8; ++k) if (tmp[k] > v0) { v0 = tmp[k]; i0 = k; }
    float v1 = -1.f; int i1 = 0;
#pragma unroll
    for (int k = 0; k < 8; ++k) if (k != i0 && tmp[k] > v1) { v1 = tmp[k]; i1 = k; }
    float e1 = expf(v1 - v0);
    float w0 = 1.f / (1.f + e1), w1 = e1 / (1.f + e1);
    w2[t * 2] = w0; w2[t * 2 + 1] = w1;
    idxb[t * 2] = i0; idxb[t * 2 + 1] = i1;
    wmat[(gg * 8 + bb) * 8 + i0] = w0;
    wmat[(gg * 8 + bb) * 8 + i1] = w1;
    needed[i0 * 8 + bb] = 1;
    needed[i1 * 8 + bb] = 1;
  }
  __syncthreads();
  if (t == 0) {
    float total = 0.f;
    for (int gg = 0; gg < 4; ++gg) {
      float us[8]; float mean = 0.f;
      for (int k = 0; k < 8; ++k) {
        float u = 0.f;
        for (int bb = 0; bb < 8; ++bb) u += go[gg][bb][k];
        us[k] = u; mean += u;
      }
      mean *= 0.125f;
      float var = 0.f;
      for (int k = 0; k < 8; ++k) { float d = us[k] - mean; var += d * d; }
      var *= (1.f / 7.f);
      total += var / (mean * mean + 1e-10f);
    }
    *lossp = total;
  }
}

// ---------------- fused prep: X transpose+split and W pre-swizzle+split ----------
// blocks 0..511: prepx (y=blk&63, b=blk>>6).  blocks 512..1535: prepw grid-stride.
__global__ __launch_bounds__(256) void k_prep(const float* __restrict__ x,
    const float* __restrict__ Wc, const float* __restrict__ Wp,
    u16* __restrict__ XTh, u16* __restrict__ XTl,
    u16* __restrict__ Wph, u16* __restrict__ Wpl,
    u16* __restrict__ Pph, u16* __restrict__ Ppl) {
  __shared__ float T[64 * 129];
  int blk = blockIdx.x;
  if (blk < 512) {
    int y = blk & 63, b = blk >> 6;
    for (int i = threadIdx.x; i < 128 * 64; i += 256) {
      int ci = i >> 6, xc = i & 63;
      T[xc * 129 + ci] = x[((size_t)(b * 128 + ci)) * HW_ + y * 64 + xc];
    }
    __syncthreads();
    for (int i = threadIdx.x; i < 64 * 128; i += 256) {
      int xc = i >> 7, ci = i & 127;
      float v = T[xc * 129 + ci];
      u16 h = f2bf(v);
      size_t o = ((size_t)(b * HW_ + y * 64 + xc)) * 128 + ci;
      XTh[o] = h;
      XTl[o] = f2bf(v - bf2f(h));
    }
  } else {
    int gid = (blk - 512) * 256 + threadIdx.x;
    int stride = 1024 * 256;
    const int N1 = 8 * 9 * 2 * 128 * 64;
    for (int g = gid; g < N1; g += stride) {
      int k = g & 63;
      int co = (g >> 6) & 127;
      int ch = (g >> 13) & 1;
      int v = g >> 14;
      int tap = v % 9, e = v / 9;
      int ci = ch * 64 + k;
      float wv = Wc[(((size_t)(e * 128 + co)) * 128 + ci) * 9 + tap];
      u16 h = f2bf(wv), lo = f2bf(wv - bf2f(h));
      int idx = (v * 2 + ch) * 8192 + co * 64 + (k ^ ((co & 7) << 3));
      Wph[idx] = h; Wpl[idx] = lo;
    }
    const int N2 = 8 * 4 * 128 * 32;
    for (int g = gid; g < N2; g += stride) {
      int k = g & 31;
      int co = (g >> 5) & 127;
      int c = (g >> 12) & 3;
      int e = g >> 14;
      int ci = c * 32 + k;
      float wv = Wp[((size_t)(e * 128 + co)) * 128 + ci];
      u16 h = f2bf(wv), lo = f2bf(wv - bf2f(h));
      int idx = (e * 4 + c) * 4096 + co * 32 + (k ^ ((co & 3) << 3));
      Pph[idx] = h; Ppl[idx] = lo;
    }
  }
}

// ---------------- fused expert via MFMA, reg-prefetch pipelined staging ----------
// grid (32 pos-tiles, b, e), 256 thr = 4 waves (2co x 2n of 64x64 each).
// Per K-stage (tap,ch): ds_write prefetched regs -> raw barrier -> lgkmcnt(0) ->
// barrier -> 96 MFMA/wave, while next stage's 16 global loads fly. No vmcnt drain.
__global__ __launch_bounds__(256, 2) void k_expert(
    const u16* __restrict__ XTh, const u16* __restrict__ XTl,
    const u16* __restrict__ Wph, const u16* __restrict__ Wpl,
    const u16* __restrict__ Pph, const u16* __restrict__ Ppl,
    const float* __restrict__ bcap, const float* __restrict__ bproj,
    const int* __restrict__ needed, const float* __restrict__ wmat,
    float* __restrict__ expb, float* __restrict__ yout, int use_exp) {
  int e = blockIdx.z, b = blockIdx.y;
  if (!needed[e * 8 + b]) return;
  int tile = blockIdx.x;
  int y0 = tile * 2;

  __shared__ __align__(16) char smem[75264];
  u16* S = (u16*)smem;
  const int Ah = 0, Al = 8192, Bh = 16384, Bl = 24576;   // u16 offsets
  const int Vh = 0, Vl = 16384, Pt = 32768;
  float* snb = (float*)(smem + 73728);
  float* fb  = (float*)(smem + 74752);

  int tid = threadIdx.x;
  int lane = tid & 63, w = tid >> 6;
  int l15 = lane & 15, l4 = lane >> 4;
  int cob = (w >> 1) * 64, nb = (w & 1) * 64;

  f32x4 zero4 = {0.f, 0.f, 0.f, 0.f};
  f32x4 acc[4][4];
#pragma unroll
  for (int i = 0; i < 4; ++i)
#pragma unroll
    for (int j = 0; j < 4; ++j) acc[i][j] = zero4;

  int sn_ = tid >> 1;
  int kh = (tid & 1) * 4;
  int srow = y0 + (sn_ >> 6);
  int scol = sn_ & 63;

  const u16* WphE = Wph + (size_t)e * 9 * 2 * 8192 + tid * 8;
  const u16* WplE = Wpl + (size_t)e * 9 * 2 * 8192 + tid * 8;

  uint4 ra[8];   // A prefetch: [0..3]=hi, [4..7]=lo
  uint4 rb[8];   // B prefetch: [0..3]=hi, [4..7]=lo

#define PREFETCH_CONV(S_)                                                   \
  {                                                                         \
    int tap = (S_) >> 1, ch = (S_) & 1;                                     \
    const u16* wsh = WphE + (tap * 2 + ch) * 8192;                          \
    const u16* wsl = WplE + (tap * 2 + ch) * 8192;                          \
    _Pragma("unroll")                                                       \
    for (int q = 0; q < 4; ++q) {                                           \
      ra[q]     = *(const uint4*)(wsh + q * 2048);                          \
      ra[4 + q] = *(const uint4*)(wsl + q * 2048);                          \
    }                                                                       \
    int dy = tap / 3 - 1, dx = tap % 3 - 1;                                 \
    int row = srow + dy, col = scol + dx;                                   \
    bool val = ((unsigned)row < 64u) && ((unsigned)col < 64u);              \
    uint4 z4 = {0u, 0u, 0u, 0u};                                            \
    _Pragma("unroll")                                                       \
    for (int i = 0; i < 8; ++i) rb[i] = z4;                                 \
    if (val) {                                                              \
      int gb_ = (b * HW_ + row * 64 + col) * 128 + ch * 64 + kh * 8;        \
      _Pragma("unroll")                                                     \
      for (int i = 0; i < 4; ++i) {                                         \
        rb[i]     = *(const uint4*)(XTh + gb_ + i * 8);                     \
        rb[4 + i] = *(const uint4*)(XTl + gb_ + i * 8);                     \
      }                                                                     \
    }                                                                       \
  }

  PREFETCH_CONV(0);

  for (int s = 0; s < 18; ++s) {
    __builtin_amdgcn_s_barrier();            // prev MFMA reads done, LDS free
#pragma unroll
    for (int q = 0; q < 4; ++q) {            // compiler auto-waits loads of stage s
      *(uint4*)(S + Ah + q * 2048 + tid * 8) = ra[q];
      *(uint4*)(S + Al + q * 2048 + tid * 8) = ra[4 + q];
    }
#pragma unroll
    for (int i = 0; i < 4; ++i) {
      int kg = kh + i;
      int wa = sn_ * 64 + ((kg * 8) ^ ((sn_ & 7) << 3));
      *(uint4*)(S + Bh + wa) = rb[i];
      *(uint4*)(S + Bl + wa) = rb[4 + i];
    }
    __builtin_amdgcn_sched_barrier(0);
    {
      int sn2 = (s < 17) ? s + 1 : 17;
      PREFETCH_CONV(sn2);                    // stays in flight across MFMA phase
    }
    __builtin_amdgcn_sched_barrier(0);
    asm volatile("s_waitcnt lgkmcnt(0)" ::: "memory");
    __builtin_amdgcn_s_barrier();            // tile ready
    __builtin_amdgcn_sched_barrier(0);
    __builtin_amdgcn_s_setprio(1);
#pragma unroll
    for (int ks = 0; ks < 2; ++ks) {
      bf16x8 fah[4], fal[4], fbh[4], fbl[4];
#pragma unroll
      for (int i = 0; i < 4; ++i) {
        int co = cob + i * 16 + l15;
        int ka = (ks * 32 + l4 * 8) ^ ((co & 7) << 3);
        fah[i] = *(const bf16x8*)(S + Ah + co * 64 + ka);
        fal[i] = *(const bf16x8*)(S + Al + co * 64 + ka);
      }
#pragma unroll
      for (int j = 0; j < 4; ++j) {
        int pn = nb + j * 16 + l15;
        int kb = (ks * 32 + l4 * 8) ^ ((pn & 7) << 3);
        fbh[j] = *(const bf16x8*)(S + Bh + pn * 64 + kb);
        fbl[j] = *(const bf16x8*)(S + Bl + pn * 64 + kb);
      }
#pragma unroll
      for (int i = 0; i < 4; ++i)
#pragma unroll
        for (int j = 0; j < 4; ++j) {
          acc[i][j] = MFMA(fah[i], fbh[j], acc[i][j]);
          acc[i][j] = MFMA(fah[i], fbl[j], acc[i][j]);
          acc[i][j] = MFMA(fal[i], fbh[j], acc[i][j]);
        }
    }
    __builtin_amdgcn_s_setprio(0);
  }

  // caps bias
#pragma unroll
  for (int i = 0; i < 4; ++i)
#pragma unroll
    for (int r = 0; r < 4; ++r) {
      float bc = bcap[e * 128 + cob + i * 16 + l4 * 4 + r];
#pragma unroll
      for (int j = 0; j < 4; ++j) acc[i][j][r] += bc;
    }

  // squash
#pragma unroll
  for (int j = 0; j < 4; ++j) {
    float p = 0.f;
#pragma unroll
    for (int i = 0; i < 4; ++i)
#pragma unroll
      for (int r = 0; r < 4; ++r) p += acc[i][j][r] * acc[i][j][r];
    p += __shfl_xor(p, 16);
    p += __shfl_xor(p, 32);
    if (lane < 16) snb[(w >> 1) * 128 + nb + j * 16 + lane] = p;
  }
  __syncthreads();
  if (tid < 128) {
    float s2 = snb[tid] + snb[128 + tid];
    fb[tid] = s2 / ((1.f + s2) * (sqrtf(s2) + 1e-8f));
  }
  __syncthreads();

  // v = u*f -> LDS bf16 hi/lo [128 pos][128 ci], swizzled
#pragma unroll
  for (int j = 0; j < 4; ++j) {
    int pn = nb + j * 16 + l15;
    float fj = fb[pn];
#pragma unroll
    for (int i = 0; i < 4; ++i) {
      int co0v = cob + i * 16 + l4 * 4;
      float v0 = acc[i][j][0] * fj, v1 = acc[i][j][1] * fj;
      float v2 = acc[i][j][2] * fj, v3 = acc[i][j][3] * fj;
      u16 h0 = f2bf(v0), h1 = f2bf(v1), h2 = f2bf(v2), h3 = f2bf(v3);
      uint2 hp; hp.x = (u32)h0 | ((u32)h1 << 16); hp.y = (u32)h2 | ((u32)h3 << 16);
      u16 q0 = f2bf(v0 - bf2f(h0)), q1 = f2bf(v1 - bf2f(h1));
      u16 q2 = f2bf(v2 - bf2f(h2)), q3 = f2bf(v3 - bf2f(h3));
      uint2 lp; lp.x = (u32)q0 | ((u32)q1 << 16); lp.y = (u32)q2 | ((u32)q3 << 16);
      int ad = pn * 128 + (co0v ^ ((pn & 7) << 3));
      *(uint2*)(S + Vh + ad) = hp;
      *(uint2*)(S + Vl + ad) = lp;
    }
  }

  // 1x1 proj, same reg-prefetch pipeline over 8 sub-stages
#pragma unroll
  for (int i = 0; i < 4; ++i)
#pragma unroll
    for (int j = 0; j < 4; ++j) acc[i][j] = zero4;

  uint4 rp0, rp1;
#define PREFETCH_PROJ(ST_)                                                  \
  {                                                                         \
    int sp_ = (ST_) >> 2, c_ = (ST_) & 3;                                   \
    const u16* ps = (sp_ ? Ppl : Pph) + (size_t)(e * 4 + c_) * 4096 +       \
                    (w * 2) * 512 + lane * 8;                               \
    rp0 = *(const uint4*)ps;                                                \
    rp1 = *(const uint4*)(ps + 512);                                        \
  }

  PREFETCH_PROJ(0);
  for (int st = 0; st < 8; ++st) {
    __builtin_amdgcn_s_barrier();
    *(uint4*)(S + Pt + (w * 2) * 512 + lane * 8) = rp0;
    *(uint4*)(S + Pt + (w * 2 + 1) * 512 + lane * 8) = rp1;
    __builtin_amdgcn_sched_barrier(0);
    {
      int st2 = (st < 7) ? st + 1 : 7;
      PREFETCH_PROJ(st2);
    }
    __builtin_amdgcn_sched_barrier(0);
    asm volatile("s_waitcnt lgkmcnt(0)" ::: "memory");   // also drains V writes
    __builtin_amdgcn_s_barrier();
    __builtin_amdgcn_sched_barrier(0);
    int sp = st >> 2, c = st & 3;
    bf16x8 af[4], bvh[4], bvl[4];
#pragma unroll
    for (int i = 0; i < 4; ++i) {
      int co = cob + i * 16 + l15;
      int ka = (l4 * 8) ^ ((co & 3) << 3);
      af[i] = *(const bf16x8*)(S + Pt + co * 32 + ka);
    }
#pragma unroll
    for (int j = 0; j < 4; ++j) {
      int pn = nb + j * 16 + l15;
      int kb = (c * 32 + l4 * 8) ^ ((pn & 7) << 3);
      bvh[j] = *(const bf16x8*)(S + Vh + pn * 128 + kb);
      bvl[j] = *(const bf16x8*)(S + Vl + pn * 128 + kb);
    }
    __builtin_amdgcn_s_setprio(1);
    if (sp == 0) {
#pragma unroll
      for (int i = 0; i < 4; ++i)
#pragma unroll
        for (int j = 0; j < 4; ++j) {
          acc[i][j] = MFMA(af[i], bvh[j], acc[i][j]);
          acc[i][j] = MFMA(af[i], bvl[j], acc[i][j]);
        }
    } else {
#pragma unroll
      for (int i = 0; i < 4; ++i)
#pragma unroll
        for (int j = 0; j < 4; ++j)
          acc[i][j] = MFMA(af[i], bvh[j], acc[i][j]);
    }
    __builtin_amdgcn_s_setprio(0);
  }

  // epilogue
  int posbase = tile * 128;
  if (use_exp) {
    float* ob = expb + ((size_t)((e * 8 + b) * 128)) * HW_;
#pragma unroll
    for (int i = 0; i < 4; ++i)
#pragma unroll
      for (int r = 0; r < 4; ++r) {
        int co = cob + i * 16 + l4 * 4 + r;
        float bp = bproj[e * 128 + co];
#pragma unroll
        for (int j = 0; j < 4; ++j) {
          int p = posbase + nb + j * 16 + l15;
          ob[(size_t)co * HW_ + p] = acc[i][j][r] + bp;
        }
      }
  } else {
    for (int g = 0; g < 4; ++g) {
      float wgt = wmat[(g * 8 + b) * 8 + e];
      if (wgt != 0.f) {
        float* ob = yout + (size_t)(g * 8 + b) * (C_ * HW_);
#pragma unroll
        for (int i = 0; i < 4; ++i)
#pragma unroll
          for (int r = 0; r < 4; ++r) {
            int co = cob + i * 16 + l4 * 4 + r;
            float bp = bproj[e * 128 + co];
#pragma unroll
            for (int j = 0; j < 4; ++j) {
              int p = posbase + nb + j * 16 + l15;
              atomicAdd(&ob[(size_t)co * HW_ + p], wgt * (acc[i][j][r] + bp));
            }
          }
      }
    }
  }
#undef PREFETCH_CONV
#undef PREFETCH_PROJ
}

// ---------------- combine ----------------
__global__ __launch_bounds__(256) void k_combine(const float* __restrict__ expb,
    const int* __restrict__ idxb, const float* __restrict__ w2,
    float* __restrict__ yout) {
  int gb = blockIdx.y;
  int b = gb & 7;
  int i0 = idxb[gb * 2], i1 = idxb[gb * 2 + 1];
  float w0 = w2[gb * 2], w1 = w2[gb * 2 + 1];
  const float4* p0 = (const float4*)(expb + (size_t)(i0 * 8 + b) * (C_ * HW_));
  const float4* p1 = (const float4*)(expb + (size_t)(i1 * 8 + b) * (C_ * HW_));
  float4* o = (float4*)(yout + (size_t)gb * (C_ * HW_));
  for (int i = blockIdx.x * 256 + threadIdx.x; i < C_ * HW_ / 4;
       i += gridDim.x * 256) {
    float4 a = p0[i], c = p1[i];
    float4 r = {w0 * a.x + w1 * c.x, w0 * a.y + w1 * c.y,
                w0 * a.z + w1 * c.z, w0 * a.w + w1 * c.w};
    o[i] = r;
  }
}

extern "C" void kernel_launch(void* const* d_in, const int* in_sizes, int n_in,
                              void* d_out, int out_size, void* d_ws, size_t ws_size,
                              hipStream_t stream) {
  const float* x  = (const float*)d_in[0];
  const float* g1 = (const float*)d_in[1];
  const float* g2 = (const float*)d_in[2];
  const float* g3 = (const float*)d_in[3];
  const float* g4 = (const float*)d_in[4];
  const float* Wc = (const float*)d_in[5];
  const float* bc = (const float*)d_in[6];
  const float* Wp = (const float*)d_in[7];
  const float* bp = (const float*)d_in[8];
  float* out = (float*)d_out;

  const size_t EXPF = (size_t)E_ * B_ * C_ * HW_;
  const size_t XTU  = (size_t)B_ * HW_ * C_;
  const size_t WSU  = (size_t)8 * 9 * 2 * 8192;
  const size_t PSU  = (size_t)8 * 4 * 4096;
  const size_t needB = EXPF * 4 + 2 * XTU * 2 + 2 * WSU * 2 + 2 * PSU * 2 + 8192;
  int use_exp = (ws_size >= needB) ? 1 : 0;

  char* p = (char*)d_ws;
  float* expb = nullptr;
  if (use_exp) { expb = (float*)p; p += EXPF * 4; }
  u16* XTh = (u16*)p; p += XTU * 2;
  u16* XTl = (u16*)p; p += XTU * 2;
  u16* Wph = (u16*)p; p += WSU * 2;
  u16* Wpl = (u16*)p; p += WSU * 2;
  u16* Pph = (u16*)p; p += PSU * 2;
  u16* Ppl = (u16*)p; p += PSU * 2;
  float* x0   = (float*)p; p += 1024 * 4;
  float* wmat = (float*)p; p += 256 * 4;
  float* w2   = (float*)p; p += 64 * 4;
  int*   idxb = (int*)p;   p += 64 * 4;
  int*   needed = (int*)p; p += 64 * 4;

  if (!use_exp)
    hipMemsetAsync(d_out, 0, (size_t)4 * B_ * C_ * HW_ * 4, stream);

  k_mean<<<dim3(B_ * C_), dim3(256), 0, stream>>>(x, x0);
  k_gate<<<dim3(1), dim3(256), 0, stream>>>(x0, g1, g2, g3, g4, wmat, w2, idxb,
                                            needed, out + (size_t)4 * B_ * C_ * HW_);
  k_prep<<<dim3(1536), dim3(256), 0, stream>>>(x, Wc, Wp, XTh, XTl, Wph, Wpl,
                                               Pph, Ppl);
  k_expert<<<dim3(32, B_, E_), dim3(256), 0, stream>>>(
      XTh, XTl, Wph, Wpl, Pph, Ppl, bc, bp, needed, wmat, expb, out, use_exp);
  if (use_exp)
    k_combine<<<dim3(64, 32), dim3(256), 0, stream>>>(expb, idxb, w2, out);
}

// Round 5
// 325.856 us; speedup vs baseline: 1.4014x; 1.4014x over previous
//
#include <hip/hip_runtime.h>
#include <math.h>

#define B_   8
#define C_   128
#define E_   8
#define HW_  4096

typedef unsigned short u16;
typedef unsigned int   u32;
typedef __attribute__((ext_vector_type(8))) short bf16x8;
typedef __attribute__((ext_vector_type(4))) float f32x4;

__device__ __forceinline__ u16 f2bf(float f) {
  u32 u = __float_as_uint(f);
  u32 r = (u + 0x7fffu + ((u >> 16) & 1u)) >> 16;
  return (u16)r;
}
__device__ __forceinline__ float bf2f(u16 h) {
  return __uint_as_float(((u32)h) << 16);
}
__device__ __forceinline__ void gld_lds16(const u16* g, u16* l) {
  __builtin_amdgcn_global_load_lds((const __attribute__((address_space(1))) u32*)g,
                                   (__attribute__((address_space(3))) u32*)(void*)l,
                                   16, 0, 0);
}
#define MFMA(a, b, c) __builtin_amdgcn_mfma_f32_16x16x32_bf16(a, b, c, 0, 0, 0)

// ---------------- channel means ----------------
__global__ __launch_bounds__(256) void k_mean(const float* __restrict__ x,
                                              float* __restrict__ x0) {
  int bc = blockIdx.x;
  const float4* p = (const float4*)(x + (size_t)bc * HW_);
  float s = 0.f;
  for (int i = threadIdx.x; i < HW_ / 4; i += 256) {
    float4 v = p[i];
    s += v.x + v.y + v.z + v.w;
  }
#pragma unroll
  for (int off = 32; off > 0; off >>= 1) s += __shfl_down(s, off);
  __shared__ float red[4];
  if ((threadIdx.x & 63) == 0) red[threadIdx.x >> 6] = s;
  __syncthreads();
  if (threadIdx.x == 0)
    x0[bc] = (red[0] + red[1] + red[2] + red[3]) * (1.f / HW_);
}

// ---------------- gates (UNCHANGED math) ----------------
__global__ __launch_bounds__(256) void k_gate(const float* __restrict__ x0,
    const float* __restrict__ g1, const float* __restrict__ g2,
    const float* __restrict__ g3, const float* __restrict__ g4,
    float* __restrict__ wmat, float* __restrict__ w2, int* __restrict__ idxb,
    int* __restrict__ needed, float* __restrict__ lossp) {
  __shared__ float go[4][8][8];
  int t = threadIdx.x;
  int g = t >> 6, b = (t >> 3) & 7, e = t & 7;
  const float* gp = (g == 0) ? g1 : (g == 1) ? g2 : (g == 2) ? g3 : g4;
  const float* xr = x0 + b * C_;
  float s = 0.f;
  for (int c = 0; c < C_; ++c) s += xr[c] * gp[c * E_ + e];
  go[g][b][e] = s;
  wmat[t] = 0.f;
  if (t < 64) needed[t] = 0;
  __syncthreads();
  if (t < 32) {
    int gg = t >> 3, bb = t & 7;
    float m = -1e30f;
#pragma unroll
    for (int k = 0; k < 8; ++k) m = fmaxf(m, go[gg][bb][k]);
    float tmp[8]; float sum = 0.f;
#pragma unroll
    for (int k = 0; k < 8; ++k) { tmp[k] = expf(go[gg][bb][k] - m); sum += tmp[k]; }
    float inv = 1.f / sum;
#pragma unroll
    for (int k = 0; k < 8; ++k) { tmp[k] *= inv; go[gg][bb][k] = tmp[k]; }
    float v0 = -1.f; int i0 = 0;
#pragma unroll
    for (int k = 0; k < 8; ++k) if (tmp[k] > v0) { v0 = tmp[k]; i0 = k; }
    float v1 = -1.f; int i1 = 0;
#pragma unroll
    for (int k = 0; k < 8; ++k) if (k != i0 && tmp[k] > v1) { v1 = tmp[k]; i1 = k; }
    float e1 = expf(v1 - v0);
    float w0 = 1.f / (1.f + e1), w1 = e1 / (1.f + e1);
    w2[t * 2] = w0; w2[t * 2 + 1] = w1;
    idxb[t * 2] = i0; idxb[t * 2 + 1] = i1;
    wmat[(gg * 8 + bb) * 8 + i0] = w0;
    wmat[(gg * 8 + bb) * 8 + i1] = w1;
    needed[i0 * 8 + bb] = 1;
    needed[i1 * 8 + bb] = 1;
  }
  __syncthreads();
  if (t == 0) {
    float total = 0.f;
    for (int gg = 0; gg < 4; ++gg) {
      float us[8]; float mean = 0.f;
      for (int k = 0; k < 8; ++k) {
        float u = 0.f;
        for (int bb = 0; bb < 8; ++bb) u += go[gg][bb][k];
        us[k] = u; mean += u;
      }
      mean *= 0.125f;
      float var = 0.f;
      for (int k = 0; k < 8; ++k) { float d = us[k] - mean; var += d * d; }
      var *= (1.f / 7.f);
      total += var / (mean * mean + 1e-10f);
    }
    *lossp = total;
  }
}

// ---------------- fused prep: X transpose+split, W pre-swizzle+split, zero page --
__global__ __launch_bounds__(256) void k_prep(const float* __restrict__ x,
    const float* __restrict__ Wc, const float* __restrict__ Wp,
    u16* __restrict__ XTh, u16* __restrict__ XTl,
    u16* __restrict__ Wph, u16* __restrict__ Wpl,
    u16* __restrict__ Pph, u16* __restrict__ Ppl, u16* __restrict__ zp) {
  __shared__ float T[64 * 129];
  int blk = blockIdx.x;
  if (blk < 512) {
    int y = blk & 63, b = blk >> 6;
    for (int i = threadIdx.x; i < 128 * 64; i += 256) {
      int ci = i >> 6, xc = i & 63;
      T[xc * 129 + ci] = x[((size_t)(b * 128 + ci)) * HW_ + y * 64 + xc];
    }
    __syncthreads();
    for (int i = threadIdx.x; i < 64 * 128; i += 256) {
      int xc = i >> 7, ci = i & 127;
      float v = T[xc * 129 + ci];
      u16 h = f2bf(v);
      size_t o = ((size_t)(b * HW_ + y * 64 + xc)) * 128 + ci;
      XTh[o] = h;
      XTl[o] = f2bf(v - bf2f(h));
    }
  } else {
    if (blk == 512 && threadIdx.x < 64) zp[threadIdx.x] = 0;
    int gid = (blk - 512) * 256 + threadIdx.x;
    int stride = 1024 * 256;
    const int N1 = 8 * 9 * 2 * 128 * 64;
    for (int g = gid; g < N1; g += stride) {
      int k = g & 63;
      int co = (g >> 6) & 127;
      int ch = (g >> 13) & 1;
      int v = g >> 14;
      int tap = v % 9, e = v / 9;
      int ci = ch * 64 + k;
      float wv = Wc[(((size_t)(e * 128 + co)) * 128 + ci) * 9 + tap];
      u16 h = f2bf(wv), lo = f2bf(wv - bf2f(h));
      int idx = (v * 2 + ch) * 8192 + co * 64 + (k ^ ((co & 7) << 3));
      Wph[idx] = h; Wpl[idx] = lo;
    }
    const int N2 = 8 * 4 * 128 * 32;
    for (int g = gid; g < N2; g += stride) {
      int k = g & 31;
      int co = (g >> 5) & 127;
      int c = (g >> 12) & 3;
      int e = g >> 14;
      int ci = c * 32 + k;
      float wv = Wp[((size_t)(e * 128 + co)) * 128 + ci];
      u16 h = f2bf(wv), lo = f2bf(wv - bf2f(h));
      int idx = (e * 4 + c) * 4096 + co * 32 + (k ^ ((co & 3) << 3));
      Pph[idx] = h; Ppl[idx] = lo;
    }
  }
}

// ---------------- fused expert: MFMA + gld_lds double-buffer, counted vmcnt -----
// grid (32 tiles, 8 b, 8 e), 512 thr = 8 waves (2 co-halves x 4 pos-quarters).
// Conv: 18 stages (9 taps x 2 ci-chunks of 64). Per stage per wave: 8 gld_lds
// issued for stage s+1, then s_waitcnt vmcnt(8), barrier, 48 MFMA, barrier.
__global__ __launch_bounds__(512, 2) void k_expert(
    const u16* __restrict__ XTh, const u16* __restrict__ XTl,
    const u16* __restrict__ Wph, const u16* __restrict__ Wpl,
    const u16* __restrict__ Pph, const u16* __restrict__ Ppl,
    const float* __restrict__ bcap, const float* __restrict__ bproj,
    const int* __restrict__ needed, const float* __restrict__ wmat,
    const u16* __restrict__ zp,
    float* __restrict__ expb, float* __restrict__ yout, int use_exp) {
  int e = blockIdx.z, b = blockIdx.y;
  if (!needed[e * 8 + b]) return;
  int tile = blockIdx.x;
  int y0 = tile * 2;

  // LDS: conv buf0 u16[0..32768) = {Ah,Al,Bh,Bl}, buf1 u16[32768..65536).
  // Proj phase aliases: Vh@0, Vl@16384, Pt0@32768, Pt1@36864 (u16).
  // snb @ byte 81920 (in buf1, used only after conv), fb @ 82944.
  __shared__ __align__(16) char smem[131072];
  u16* S = (u16*)smem;
  float* snb = (float*)(smem + 81920);   // [2][128]
  float* fb  = (float*)(smem + 82944);   // [128]

  int tid = threadIdx.x;
  int lane = tid & 63, w = tid >> 6;
  int l15 = lane & 15, l4 = lane >> 4;
  int cob = (w >> 2) * 64, nb = (w & 3) * 32;

  f32x4 zero4 = {0.f, 0.f, 0.f, 0.f};
  f32x4 acc[4][2];
#pragma unroll
  for (int i = 0; i < 4; ++i)
#pragma unroll
    for (int j = 0; j < 2; ++j) acc[i][j] = zero4;

  const u16* WphE = Wph + (size_t)e * 9 * 2 * 8192;
  const u16* WplE = Wpl + (size_t)e * 9 * 2 * 8192;

  // B-staging lane constants: instr q covers rows sn0q..sn0q+7 (8 x 128B)
  int Lr = lane >> 3, s_ = lane & 7;

  auto STAGE = [&](int st, int bufU16) {
    int tap = st >> 1, ch = st & 1;
    const u16* wsh = WphE + (tap * 2 + ch) * 8192;
    const u16* wsl = WplE + (tap * 2 + ch) * 8192;
    gld_lds16(wsh + (w * 2 + 0) * 512 + lane * 8, S + bufU16 + (w * 2 + 0) * 512);
    gld_lds16(wsh + (w * 2 + 1) * 512 + lane * 8, S + bufU16 + (w * 2 + 1) * 512);
    gld_lds16(wsl + (w * 2 + 0) * 512 + lane * 8, S + bufU16 + 8192 + (w * 2 + 0) * 512);
    gld_lds16(wsl + (w * 2 + 1) * 512 + lane * 8, S + bufU16 + 8192 + (w * 2 + 1) * 512);
    int dy = tap / 3 - 1, dx = tap % 3 - 1;
#pragma unroll
    for (int q = 0; q < 2; ++q) {
      int sn = (w * 2 + q) * 8 + Lr;
      int g  = s_ ^ (sn & 7);
      int gy = y0 + (sn >> 6) + dy;
      int gx = (sn & 63) + dx;
      bool val = ((unsigned)gy < 64u) && ((unsigned)gx < 64u);
      int go_ = ((b << 12) + gy * 64 + gx) * 128 + ch * 64 + g * 8;
      const u16* sh = val ? (XTh + go_) : zp;
      const u16* sl = val ? (XTl + go_) : zp;
      gld_lds16(sh, S + bufU16 + 16384 + (w * 2 + q) * 512);
      gld_lds16(sl, S + bufU16 + 24576 + (w * 2 + q) * 512);
    }
  };

  STAGE(0, 0);
  for (int s = 0; s < 18; ++s) {
    int cur = (s & 1) * 32768;
    if (s < 17) {
      STAGE(s + 1, ((s + 1) & 1) * 32768);
      asm volatile("s_waitcnt vmcnt(8)" ::: "memory");
    } else {
      asm volatile("s_waitcnt vmcnt(0)" ::: "memory");
    }
    __builtin_amdgcn_s_barrier();
    __builtin_amdgcn_sched_barrier(0);
    __builtin_amdgcn_s_setprio(1);
#pragma unroll
    for (int ks = 0; ks < 2; ++ks) {
      bf16x8 fah[4], fal[4], fbh[2], fbl[2];
#pragma unroll
      for (int i = 0; i < 4; ++i) {
        int co = cob + i * 16 + l15;
        int ka = (ks * 32 + l4 * 8) ^ ((co & 7) << 3);
        fah[i] = *(const bf16x8*)(S + cur + co * 64 + ka);
        fal[i] = *(const bf16x8*)(S + cur + 8192 + co * 64 + ka);
      }
#pragma unroll
      for (int j = 0; j < 2; ++j) {
        int pn = nb + j * 16 + l15;
        int kb = (ks * 32 + l4 * 8) ^ ((pn & 7) << 3);
        fbh[j] = *(const bf16x8*)(S + cur + 16384 + pn * 64 + kb);
        fbl[j] = *(const bf16x8*)(S + cur + 24576 + pn * 64 + kb);
      }
#pragma unroll
      for (int i = 0; i < 4; ++i)
#pragma unroll
        for (int j = 0; j < 2; ++j) {
          acc[i][j] = MFMA(fah[i], fbh[j], acc[i][j]);
          acc[i][j] = MFMA(fah[i], fbl[j], acc[i][j]);
          acc[i][j] = MFMA(fal[i], fbh[j], acc[i][j]);
        }
    }
    __builtin_amdgcn_s_setprio(0);
    __builtin_amdgcn_sched_barrier(0);
    __builtin_amdgcn_s_barrier();
  }

  // caps bias
#pragma unroll
  for (int i = 0; i < 4; ++i)
#pragma unroll
    for (int r = 0; r < 4; ++r) {
      float bc = bcap[e * 128 + cob + i * 16 + l4 * 4 + r];
#pragma unroll
      for (int j = 0; j < 2; ++j) acc[i][j][r] += bc;
    }

  // squash partial sums (per wave: its 64-co half), then combine halves
#pragma unroll
  for (int j = 0; j < 2; ++j) {
    float p = 0.f;
#pragma unroll
    for (int i = 0; i < 4; ++i)
#pragma unroll
      for (int r = 0; r < 4; ++r) p += acc[i][j][r] * acc[i][j][r];
    p += __shfl_xor(p, 16);
    p += __shfl_xor(p, 32);
    if (lane < 16) snb[(w >> 2) * 128 + nb + j * 16 + lane] = p;
  }
  __syncthreads();
  if (tid < 128) {
    float s2 = snb[tid] + snb[128 + tid];
    fb[tid] = s2 / ((1.f + s2) * (sqrtf(s2) + 1e-8f));
  }
  __syncthreads();

  // v = u*f -> LDS bf16 hi/lo [128 pos][128 ci], swizzled (aliases conv buf0)
#pragma unroll
  for (int j = 0; j < 2; ++j) {
    int pn = nb + j * 16 + l15;
    float fj = fb[pn];
#pragma unroll
    for (int i = 0; i < 4; ++i) {
      int co0v = cob + i * 16 + l4 * 4;
      float v0 = acc[i][j][0] * fj, v1 = acc[i][j][1] * fj;
      float v2 = acc[i][j][2] * fj, v3 = acc[i][j][3] * fj;
      u16 h0 = f2bf(v0), h1 = f2bf(v1), h2 = f2bf(v2), h3 = f2bf(v3);
      uint2 hp; hp.x = (u32)h0 | ((u32)h1 << 16); hp.y = (u32)h2 | ((u32)h3 << 16);
      u16 q0 = f2bf(v0 - bf2f(h0)), q1 = f2bf(v1 - bf2f(h1));
      u16 q2 = f2bf(v2 - bf2f(h2)), q3 = f2bf(v3 - bf2f(h3));
      uint2 lp; lp.x = (u32)q0 | ((u32)q1 << 16); lp.y = (u32)q2 | ((u32)q3 << 16);
      int ad = pn * 128 + (co0v ^ ((pn & 7) << 3));
      *(uint2*)(S + ad) = hp;
      *(uint2*)(S + 16384 + ad) = lp;
    }
  }
  __syncthreads();

  // 1x1 proj: 8 stages (2 splits x 4 ci-chunks of 32), Pt double-buffered
#pragma unroll
  for (int i = 0; i < 4; ++i)
#pragma unroll
    for (int j = 0; j < 2; ++j) acc[i][j] = zero4;

  auto STAGE_P = [&](int st, int bufU16) {
    const u16* ps = (st >= 4 ? Ppl : Pph) + (size_t)(e * 4 + (st & 3)) * 4096 +
                    w * 512 + lane * 8;
    gld_lds16(ps, S + bufU16 + w * 512);
  };

  STAGE_P(0, 32768);
  for (int st = 0; st < 8; ++st) {
    int curP = 32768 + (st & 1) * 4096;
    if (st < 7) {
      STAGE_P(st + 1, 32768 + ((st + 1) & 1) * 4096);
      asm volatile("s_waitcnt vmcnt(1)" ::: "memory");
    } else {
      asm volatile("s_waitcnt vmcnt(0)" ::: "memory");
    }
    __builtin_amdgcn_s_barrier();
    __builtin_amdgcn_sched_barrier(0);
    int sp = st >> 2, c = st & 3;
    bf16x8 af[4], bvh[2], bvl[2];
#pragma unroll
    for (int i = 0; i < 4; ++i) {
      int co = cob + i * 16 + l15;
      int ka = (l4 * 8) ^ ((co & 3) << 3);
      af[i] = *(const bf16x8*)(S + curP + co * 32 + ka);
    }
#pragma unroll
    for (int j = 0; j < 2; ++j) {
      int pn = nb + j * 16 + l15;
      int kb = (c * 32 + l4 * 8) ^ ((pn & 7) << 3);
      bvh[j] = *(const bf16x8*)(S + pn * 128 + kb);
      bvl[j] = *(const bf16x8*)(S + 16384 + pn * 128 + kb);
    }
    __builtin_amdgcn_s_setprio(1);
    if (sp == 0) {
#pragma unroll
      for (int i = 0; i < 4; ++i)
#pragma unroll
        for (int j = 0; j < 2; ++j) {
          acc[i][j] = MFMA(af[i], bvh[j], acc[i][j]);
          acc[i][j] = MFMA(af[i], bvl[j], acc[i][j]);
        }
    } else {
#pragma unroll
      for (int i = 0; i < 4; ++i)
#pragma unroll
        for (int j = 0; j < 2; ++j)
          acc[i][j] = MFMA(af[i], bvh[j], acc[i][j]);
    }
    __builtin_amdgcn_s_setprio(0);
    __builtin_amdgcn_sched_barrier(0);
    __builtin_amdgcn_s_barrier();
  }

  // epilogue: + proj bias, store
  int posbase = tile * 128;
  if (use_exp) {
    float* ob = expb + ((size_t)((e * 8 + b) * 128)) * HW_;
#pragma unroll
    for (int i = 0; i < 4; ++i)
#pragma unroll
      for (int r = 0; r < 4; ++r) {
        int co = cob + i * 16 + l4 * 4 + r;
        float bp = bproj[e * 128 + co];
#pragma unroll
        for (int j = 0; j < 2; ++j) {
          int p = posbase + nb + j * 16 + l15;
          ob[(size_t)co * HW_ + p] = acc[i][j][r] + bp;
        }
      }
  } else {
    for (int g = 0; g < 4; ++g) {
      float wgt = wmat[(g * 8 + b) * 8 + e];
      if (wgt != 0.f) {
        float* ob = yout + (size_t)(g * 8 + b) * (C_ * HW_);
#pragma unroll
        for (int i = 0; i < 4; ++i)
#pragma unroll
          for (int r = 0; r < 4; ++r) {
            int co = cob + i * 16 + l4 * 4 + r;
            float bp = bproj[e * 128 + co];
#pragma unroll
            for (int j = 0; j < 2; ++j) {
              int p = posbase + nb + j * 16 + l15;
              atomicAdd(&ob[(size_t)co * HW_ + p], wgt * (acc[i][j][r] + bp));
            }
          }
      }
    }
  }
}

// ---------------- combine ----------------
__global__ __launch_bounds__(256) void k_combine(const float* __restrict__ expb,
    const int* __restrict__ idxb, const float* __restrict__ w2,
    float* __restrict__ yout) {
  int gb = blockIdx.y;
  int b = gb & 7;
  int i0 = idxb[gb * 2], i1 = idxb[gb * 2 + 1];
  float w0 = w2[gb * 2], w1 = w2[gb * 2 + 1];
  const float4* p0 = (const float4*)(expb + (size_t)(i0 * 8 + b) * (C_ * HW_));
  const float4* p1 = (const float4*)(expb + (size_t)(i1 * 8 + b) * (C_ * HW_));
  float4* o = (float4*)(yout + (size_t)gb * (C_ * HW_));
  for (int i = blockIdx.x * 256 + threadIdx.x; i < C_ * HW_ / 4;
       i += gridDim.x * 256) {
    float4 a = p0[i], c = p1[i];
    float4 r = {w0 * a.x + w1 * c.x, w0 * a.y + w1 * c.y,
                w0 * a.z + w1 * c.z, w0 * a.w + w1 * c.w};
    o[i] = r;
  }
}

extern "C" void kernel_launch(void* const* d_in, const int* in_sizes, int n_in,
                              void* d_out, int out_size, void* d_ws, size_t ws_size,
                              hipStream_t stream) {
  const float* x  = (const float*)d_in[0];
  const float* g1 = (const float*)d_in[1];
  const float* g2 = (const float*)d_in[2];
  const float* g3 = (const float*)d_in[3];
  const float* g4 = (const float*)d_in[4];
  const float* Wc = (const float*)d_in[5];
  const float* bc = (const float*)d_in[6];
  const float* Wp = (const float*)d_in[7];
  const float* bp = (const float*)d_in[8];
  float* out = (float*)d_out;

  const size_t EXPF = (size_t)E_ * B_ * C_ * HW_;
  const size_t XTU  = (size_t)B_ * HW_ * C_;
  const size_t WSU  = (size_t)8 * 9 * 2 * 8192;
  const size_t PSU  = (size_t)8 * 4 * 4096;
  const size_t needB = EXPF * 4 + 2 * XTU * 2 + 2 * WSU * 2 + 2 * PSU * 2 + 16384;
  int use_exp = (ws_size >= needB) ? 1 : 0;

  char* p = (char*)d_ws;
  float* expb = nullptr;
  if (use_exp) { expb = (float*)p; p += EXPF * 4; }
  u16* XTh = (u16*)p; p += XTU * 2;
  u16* XTl = (u16*)p; p += XTU * 2;
  u16* Wph = (u16*)p; p += WSU * 2;
  u16* Wpl = (u16*)p; p += WSU * 2;
  u16* Pph = (u16*)p; p += PSU * 2;
  u16* Ppl = (u16*)p; p += PSU * 2;
  float* x0   = (float*)p; p += 1024 * 4;
  float* wmat = (float*)p; p += 256 * 4;
  float* w2   = (float*)p; p += 64 * 4;
  int*   idxb = (int*)p;   p += 64 * 4;
  int*   needed = (int*)p; p += 64 * 4;
  u16*   zp = (u16*)p;     p += 128;

  if (!use_exp)
    hipMemsetAsync(d_out, 0, (size_t)4 * B_ * C_ * HW_ * 4, stream);

  k_mean<<<dim3(B_ * C_), dim3(256), 0, stream>>>(x, x0);
  k_gate<<<dim3(1), dim3(256), 0, stream>>>(x0, g1, g2, g3, g4, wmat, w2, idxb,
                                            needed, out + (size_t)4 * B_ * C_ * HW_);
  k_prep<<<dim3(1536), dim3(256), 0, stream>>>(x, Wc, Wp, XTh, XTl, Wph, Wpl,
                                               Pph, Ppl, zp);
  k_expert<<<dim3(32, B_, E_), dim3(512), 0, stream>>>(
      XTh, XTl, Wph, Wpl, Pph, Ppl, bc, bp, needed, wmat, zp, expb, out, use_exp);
  if (use_exp)
    k_combine<<<dim3(64, 32), dim3(256), 0, stream>>>(expb, idxb, w2, out);
}